// Round 7
// baseline (1316.229 us; speedup 1.0000x reference)
//
#include <hip/hip_runtime.h>

typedef unsigned short u16;
typedef unsigned int u32;
typedef __attribute__((ext_vector_type(8))) short bf16x8;
typedef __attribute__((ext_vector_type(4))) float f32x4;

#define NND 50000
#define NE 800000
#define NH 8
#define ND 32
#define NTY 5
#define NBIN 782            // bins of 64 dst nodes: ceil(50000/64), even
#define CHK 4096            // edges per binning block
#define NCH 196             // ceil(NE/CHK)
#define NM (NBIN * NCH)     // 153272 count-matrix entries

__device__ inline u16 f2bf(float x){
  u32 u = __float_as_uint(x);
  return (u16)((u + 0x7FFFu + ((u >> 16) & 1u)) >> 16);
}

// ---------------- W pre-convert: fc_w fp32 -> bf16 once
__global__ __launch_bounds__(256) void wcvt_k(const float* __restrict__ W,
                                              u16* __restrict__ Wb){
  int i = (blockIdx.x * 256 + threadIdx.x) * 4;
  f32x4 v = __builtin_nontemporal_load((const f32x4*)(W + i));
  ushort4 h = make_ushort4(f2bf(v[0]), f2bf(v[1]), f2bf(v[2]), f2bf(v[3]));
  *(ushort4*)(Wb + i) = h;
}

// ---------------- GEMM: feat[M,256] @ fc_w[256,256]^T -> feat_src bf16, stored
// PAIR-QUARTER-MAJOR: fsrc[q][node][64] (q = col>>6) -> 128B rows so agg's
// gather is one full cache line per edge (request-rate floor; round-3 lesson).
__global__ __launch_bounds__(512, 4) void gemm_k(const float* __restrict__ A,
                                                 const u16* __restrict__ Wb,
                                                 u16* __restrict__ C, int M){
  __shared__ u16 As[128 * 64];  // 16KB: addr(r,ch) u16s = r*64 + ((ch^(r&7))*8)
  __shared__ u16 Ws[256 * 64];  // 32KB: addr(n,ch) u16s = n*64 + ((ch^(n&7))*8)
  const int tid  = threadIdx.x;
  const int m0   = blockIdx.x * 128;
  const int lane = tid & 63, wid = tid >> 6;
  const int wm = (wid >> 2) * 64, wn = (wid & 3) * 64;
  const int ml = lane & 15, quad = lane >> 4;

  f32x4 acc[4][4] = {};

  const int ra = tid >> 2, ca0 = (tid & 3) * 2;
  int rag = m0 + ra; if (rag >= M) rag = M - 1;   // clamp: garbage rows never stored
  const float* aRow = A + (size_t)rag * 256;
  const int rw = tid >> 1, hw = tid & 1;
  const u16* wRow = Wb + (size_t)rw * 256;

  for (int k0 = 0; k0 < 256; k0 += 64){
    #pragma unroll
    for (int q = 0; q < 2; q++){
      int ch = ca0 + q;
      f32x4 v0 = __builtin_nontemporal_load((const f32x4*)(aRow + k0 + ch * 8));
      f32x4 v1 = __builtin_nontemporal_load((const f32x4*)(aRow + k0 + ch * 8 + 4));
      ushort4 h0 = make_ushort4(f2bf(v0[0]), f2bf(v0[1]), f2bf(v0[2]), f2bf(v0[3]));
      ushort4 h1 = make_ushort4(f2bf(v1[0]), f2bf(v1[1]), f2bf(v1[2]), f2bf(v1[3]));
      u16* p = As + ra * 64 + ((ch ^ (ra & 7)) * 8);
      *(ushort4*)p = h0;
      *(ushort4*)(p + 4) = h1;
    }
    #pragma unroll
    for (int q = 0; q < 4; q++){
      int ch = hw * 4 + q;
      uint4 wv = *(const uint4*)(wRow + k0 + ch * 8);
      *(uint4*)(Ws + rw * 64 + ((ch ^ (rw & 7)) * 8)) = wv;
    }
    __syncthreads();
    #pragma unroll
    for (int kk = 0; kk < 64; kk += 32){
      bf16x8 af[4], wf[4];
      const int cA = (kk >> 3) + quad;
      #pragma unroll
      for (int t = 0; t < 4; t++){
        int r = wm + t * 16 + ml;
        af[t] = *(const bf16x8*)(As + r * 64 + ((cA ^ (r & 7)) * 8));
      }
      #pragma unroll
      for (int t = 0; t < 4; t++){
        int n = wn + t * 16 + ml;
        wf[t] = *(const bf16x8*)(Ws + n * 64 + ((cA ^ (n & 7)) * 8));
      }
      #pragma unroll
      for (int i = 0; i < 4; i++)
        #pragma unroll
        for (int j = 0; j < 4; j++)
          acc[i][j] = __builtin_amdgcn_mfma_f32_16x16x32_bf16(af[i], wf[j], acc[i][j], 0, 0, 0);
    }
    __syncthreads();
  }
  const size_t qoff = (size_t)(wn >> 6) * NND * 64;
  #pragma unroll
  for (int i = 0; i < 4; i++){
    #pragma unroll
    for (int rr = 0; rr < 4; rr++){
      int row = m0 + wm + i * 16 + quad * 4 + rr;
      if (row < M){
        u16* crow = C + qoff + (size_t)row * 64;
        #pragma unroll
        for (int j = 0; j < 4; j++)
          __builtin_nontemporal_store(f2bf(acc[i][j][rr]), crow + j * 16 + ml);
      }
    }
  }
}

// ---------------- hist: per-(chunk, bin) edge counts. LDS histogram -- ZERO
// global atomics (round-6 lesson: per-edge global ret-atomics = ~50us at the
// coherence point, ~64B fabric write each; LDS atomics are per-CU and cheap).
__global__ __launch_bounds__(256) void hist_k(const int* __restrict__ dst,
                                              int* __restrict__ mat){
  __shared__ int h[NBIN];
  int b = blockIdx.x, tid = threadIdx.x;
  for (int i = tid; i < NBIN; i += 256) h[i] = 0;
  __syncthreads();
  int base = b * CHK;
  #pragma unroll
  for (int j = 0; j < CHK / 256; j++){
    int e = base + j * 256 + tid;
    if (e < NE) atomicAdd(&h[dst[e] >> 6], 1);
  }
  __syncthreads();
  // bin-major matrix (scan order); 613KB total -> L2 absorbs the stride
  for (int i = tid; i < NBIN; i += 256) mat[i * NCH + b] = h[i];
}

// ---------------- scan over NM entries -> local offsets + block sums
__global__ __launch_bounds__(256) void scan1_k(const int* __restrict__ in,
                                               int* __restrict__ out,
                                               int* __restrict__ bsum){
  __shared__ int lds[256];
  int b = blockIdx.x, tid = threadIdx.x;
  int base = b * 1024 + tid * 4;
  int d[4]; int tsum = 0;
  #pragma unroll
  for (int j = 0; j < 4; j++){
    int v = (base + j < NM) ? in[base + j] : 0;
    d[j] = tsum; tsum += v;
  }
  lds[tid] = tsum; __syncthreads();
  for (int off = 1; off < 256; off <<= 1){
    int v = (tid >= off) ? lds[tid - off] : 0;
    __syncthreads();
    lds[tid] += v;
    __syncthreads();
  }
  int excl = lds[tid] - tsum;
  #pragma unroll
  for (int j = 0; j < 4; j++)
    if (base + j < NM) out[base + j] = excl + d[j];
  if (tid == 255) bsum[b] = lds[tid];
}

__global__ __launch_bounds__(256) void scan2_k(const int* __restrict__ bsum,
                                               int* __restrict__ bbase, int nb){
  __shared__ int l[256];
  int tid = threadIdx.x;
  int v = (tid < nb) ? bsum[tid] : 0;
  l[tid] = v; __syncthreads();
  for (int off = 1; off < 256; off <<= 1){
    int u = (tid >= off) ? l[tid - off] : 0;
    __syncthreads();
    l[tid] += u;
    __syncthreads();
  }
  bbase[tid] = l[tid] - v;
}

// ---------------- scatter into bin-contiguous ebuf via LDS cursors (no global
// atomics). entry = (dlow6 << 19) | (src16 << 3) | etype3
__global__ __launch_bounds__(256) void scat_k(const int* __restrict__ dst,
                                              const int* __restrict__ src,
                                              const int* __restrict__ ef,
                                              const int* __restrict__ mscan,
                                              const int* __restrict__ bbase,
                                              int* __restrict__ ebuf){
  __shared__ int cur[NBIN];
  int b = blockIdx.x, tid = threadIdx.x;
  for (int i = tid; i < NBIN; i += 256){
    int m = i * NCH + b;
    cur[i] = mscan[m] + bbase[m >> 10];
  }
  __syncthreads();
  int base = b * CHK;
  #pragma unroll
  for (int j = 0; j < CHK / 256; j++){
    int e = base + j * 256 + tid;
    if (e < NE){
      int d = dst[e];
      int r = atomicAdd(&cur[d >> 6], 1);   // LDS ret-atomic: cheap
      ebuf[r] = ((d & 63) << 19) | (src[e] << 3) | ef[e];
    }
  }
}

// ---------------- attn output: attn[e,h] = wl[type,h] * rdq[h>>1][dst][h&1]
__global__ __launch_bounds__(256) void attn_k(const int* __restrict__ dst,
                                              const int* __restrict__ ef,
                                              const float* __restrict__ rdq,
                                              const float* __restrict__ emb,
                                              float* __restrict__ attn){
  __shared__ float wl[40];
  int tid = threadIdx.x;
  if (tid < 40){
    int t = tid >> 3, h = tid & 7;
    float m = emb[h];
    for (int tt = 1; tt < NTY; ++tt) m = fmaxf(m, emb[tt * 8 + h]);
    wl[tid] = expf(emb[t * 8 + h] - m);
  }
  __syncthreads();
  int e = blockIdx.x * 256 + tid;
  if (e >= NE) return;
  int d = dst[e], t = ef[e];
  const float* wr = wl + t * 8;
  f32x4 o0, o1;
  #pragma unroll
  for (int q = 0; q < 4; q++){
    float2 rv = *(const float2*)(rdq + ((size_t)q * NND + d) * 2);
    float a = wr[2 * q] * rv.x, bb = wr[2 * q + 1] * rv.y;
    if (q < 2){ o0[2 * q] = a; o0[2 * q + 1] = bb; }
    else      { o1[2 * (q - 2)] = a; o1[2 * (q - 2) + 1] = bb; }
  }
  __builtin_nontemporal_store(o0, (f32x4*)(attn + (size_t)e * 8));
  __builtin_nontemporal_store(o1, (f32x4*)(attn + (size_t)e * 8 + 4));
}

// ---------------- aggregation, EDGE-PARALLEL: one block per (bin=64 nodes, q).
// XCD-pinned pair-quarters (verified r3/r4). Block sweeps its bin's CONTIGUOUS
// edge run; 8 lanes/edge gather one 128B fsrc line (request floor); products
// accumulate into LDS acc[64][65] via ds_add_f32 (stride 65 -> random dlow
// spreads across all 32 banks). No per-node (s,e), no degree imbalance, no
// straggler waves (work/block = ~1023 edges flat). ~17KB LDS -> 8 blocks/CU.
__global__ __launch_bounds__(256) void agg_k(const u16* __restrict__ fsrc,
                                             const int* __restrict__ ebuf,
                                             const int* __restrict__ mscan,
                                             const int* __restrict__ bbase,
                                             const float* __restrict__ emb,
                                             float* __restrict__ rst,
                                             float* __restrict__ rdq){
  __shared__ float accm[64 * 65 + 128];   // acc[d][65] + ss[d][2] at 4160
  __shared__ float wlq[16];               // [type][hh] for this q (10 used)
  const int tid = threadIdx.x;
  const int c   = blockIdx.x & 7;         // XCD (HW round-robin)
  const int q   = c >> 1;                 // pair-quarter pinned to XCD pair
  const int bin = (blockIdx.x >> 3) * 2 + (c & 1);
  if (tid < 10){
    int t = tid >> 1, hh = tid & 1;
    int hcol = 2 * q + hh;
    float m = emb[hcol];
    for (int tt = 1; tt < NTY; ++tt) m = fmaxf(m, emb[tt * 8 + hcol]);
    wlq[tid] = expf(emb[t * 8 + hcol] - m);
  }
  for (int i = tid; i < 64 * 65 + 128; i += 256) accm[i] = 0.f;
  __syncthreads();
  const int m0 = bin * NCH;
  const int s  = mscan[m0] + bbase[m0 >> 10];
  int e;
  if (bin == NBIN - 1) e = NE;
  else { int m1 = (bin + 1) * NCH; e = mscan[m1] + bbase[m1 >> 10]; }
  const int j  = tid & 7;                 // 8 lanes per edge, 16B each
  const int eg = tid >> 3;                // 32 edges in flight per block-iter
  const u16* qbase = fsrc + (size_t)q * (NND * 64) + j * 8;
  const int hsel = (j >> 2);              // head-within-quarter this lane feeds

#define EDGE_BODY(EI) {                                                   \
    int p = ebuf[EI];                                                     \
    int dlow = (p >> 19) & 63;                                            \
    int sv = (p >> 3) & 0xFFFF;                                           \
    float w = wlq[(p & 7) * 2 + hsel];                                    \
    uint4 v = *(const uint4*)(qbase + (size_t)sv * 64);                   \
    float* ar = accm + dlow * 65 + j * 8;                                 \
    atomicAdd(ar + 0, w * __uint_as_float(v.x << 16));                    \
    atomicAdd(ar + 1, w * __uint_as_float(v.x & 0xFFFF0000u));            \
    atomicAdd(ar + 2, w * __uint_as_float(v.y << 16));                    \
    atomicAdd(ar + 3, w * __uint_as_float(v.y & 0xFFFF0000u));            \
    atomicAdd(ar + 4, w * __uint_as_float(v.z << 16));                    \
    atomicAdd(ar + 5, w * __uint_as_float(v.z & 0xFFFF0000u));            \
    atomicAdd(ar + 6, w * __uint_as_float(v.w << 16));                    \
    atomicAdd(ar + 7, w * __uint_as_float(v.w & 0xFFFF0000u));            \
    if ((j & 3) == 0) atomicAdd(accm + 4160 + dlow * 2 + hsel, w);        \
  }

  int i = s + eg;
  for (; i + 96 < e; i += 128){           // 4 independent gather chains/lane
    EDGE_BODY(i); EDGE_BODY(i + 32); EDGE_BODY(i + 64); EDGE_BODY(i + 96);
  }
  for (; i < e; i += 32) EDGE_BODY(i);
#undef EDGE_BODY

  __syncthreads();
  // epilogue: thread (dlow = tid>>2, seg = tid&3) writes 16 floats of its row
  const int dlow = tid >> 2, seg = tid & 3;
  const int node = bin * 64 + dlow;
  if (node >= NND) return;
  float ssv = accm[4160 + dlow * 2 + (seg >> 1)];
  float inv = 1.f / (ssv + 1e-12f);
  const float* ar = accm + dlow * 65 + seg * 16;
  float* orow = rst + (size_t)node * 256 + q * 64 + seg * 16;
  #pragma unroll
  for (int u4 = 0; u4 < 4; u4++){
    f32x4 o;
    o[0] = ar[u4 * 4 + 0] * inv; o[1] = ar[u4 * 4 + 1] * inv;
    o[2] = ar[u4 * 4 + 2] * inv; o[3] = ar[u4 * 4 + 3] * inv;
    __builtin_nontemporal_store(o, (f32x4*)(orow + u4 * 4));
  }
  if (seg == 0){
    float s1 = accm[4160 + dlow * 2 + 1];
    __builtin_nontemporal_store(inv, rdq + ((size_t)q * NND + node) * 2);
    __builtin_nontemporal_store(1.f / (s1 + 1e-12f),
                                rdq + ((size_t)q * NND + node) * 2 + 1);
  }
}

extern "C" void kernel_launch(void* const* d_in, const int* in_sizes, int n_in,
                              void* d_out, int out_size, void* d_ws, size_t ws_size,
                              hipStream_t stream) {
  const float* feat = (const float*)d_in[0];
  const float* fcw  = (const float*)d_in[1];
  const float* emb  = (const float*)d_in[2];
  const int*   ef   = (const int*)d_in[3];
  const int*   src  = (const int*)d_in[4];
  const int*   dst  = (const int*)d_in[5];

  float* rst  = (float*)d_out;                         // [50000, 8, 32]
  float* attn = (float*)d_out + (size_t)NND * NH * ND; // [800000, 8]

  char* ws = (char*)d_ws;
  size_t o = 0;
  u16* fsrc    = (u16*)(ws + o);   o += (size_t)NND * 256 * 2;   // 25.6 MB (pair-quarter-major)
  int* ebuf    = (int*)(ws + o);   o += (size_t)NE * 4;          // 3.2 MB (bin-contiguous)
  int* mat     = (int*)(ws + o);   o += (size_t)NM * 4 + 512;    // 613 KB
  int* mscan   = (int*)(ws + o);   o += (size_t)NM * 4 + 512;    // 613 KB
  float* rdq   = (float*)(ws + o); o += (size_t)NND * NH * 4;    // 1.6 MB [4][NND][2]
  u16* wb      = (u16*)(ws + o);   o += (size_t)256 * 256 * 2;   // 128 KB
  int* bsum    = (int*)(ws + o);   o += 1024;                    // 256 ints
  int* bbase   = (int*)(ws + o);   o += 1024;                    // 256 ints

  wcvt_k<<<64, 256, 0, stream>>>(fcw, wb);
  gemm_k<<<391, 512, 0, stream>>>(feat, wb, fsrc, NND);
  hist_k<<<NCH, 256, 0, stream>>>(dst, mat);
  scan1_k<<<(NM + 1023) / 1024, 256, 0, stream>>>(mat, mscan, bsum);
  scan2_k<<<1, 256, 0, stream>>>(bsum, bbase, (NM + 1023) / 1024);
  scat_k<<<NCH, 256, 0, stream>>>(dst, src, ef, mscan, bbase, ebuf);
  agg_k<<<8 * (NBIN / 2), 256, 0, stream>>>(fsrc, ebuf, mscan, bbase, emb, rst, rdq);
  attn_k<<<(NE + 255) / 256, 256, 0, stream>>>(dst, ef, rdq, emb, attn);
}

// Round 8
// 246.724 us; speedup vs baseline: 5.3348x; 5.3348x over previous
//
#include <hip/hip_runtime.h>

typedef unsigned short u16;
typedef unsigned int u32;
typedef __attribute__((ext_vector_type(8))) short bf16x8;
typedef __attribute__((ext_vector_type(4))) float f32x4;
typedef __attribute__((ext_vector_type(2))) float f32x2;

#define NND 50000
#define NE 800000
#define NH 8
#define ND 32
#define NTY 5
#define NBIN 782            // bins of 64 dst nodes: ceil(50000/64), even
#define CHK 4096            // edges per binning block
#define NCH 196             // ceil(NE/CHK)
#define NM (NBIN * NCH)     // 153272 count-matrix entries

__device__ inline u16 f2bf(float x){
  u32 u = __float_as_uint(x);
  return (u16)((u + 0x7FFFu + ((u >> 16) & 1u)) >> 16);
}

// ---------------- W pre-convert: fc_w fp32 -> bf16 once
__global__ __launch_bounds__(256) void wcvt_k(const float* __restrict__ W,
                                              u16* __restrict__ Wb){
  int i = (blockIdx.x * 256 + threadIdx.x) * 4;
  f32x4 v = __builtin_nontemporal_load((const f32x4*)(W + i));
  ushort4 h = make_ushort4(f2bf(v[0]), f2bf(v[1]), f2bf(v[2]), f2bf(v[3]));
  *(ushort4*)(Wb + i) = h;
}

// ---------------- GEMM: feat[M,256] @ fc_w[256,256]^T -> feat_src bf16, stored
// PAIR-QUARTER-MAJOR: fsrc[q][node][64] (q = col>>6) -> 128B rows so agg's
// gather is one full cache line per edge (request-rate floor; round-3 lesson).
__global__ __launch_bounds__(512, 4) void gemm_k(const float* __restrict__ A,
                                                 const u16* __restrict__ Wb,
                                                 u16* __restrict__ C, int M){
  __shared__ u16 As[128 * 64];  // 16KB: addr(r,ch) u16s = r*64 + ((ch^(r&7))*8)
  __shared__ u16 Ws[256 * 64];  // 32KB: addr(n,ch) u16s = n*64 + ((ch^(n&7))*8)
  const int tid  = threadIdx.x;
  const int m0   = blockIdx.x * 128;
  const int lane = tid & 63, wid = tid >> 6;
  const int wm = (wid >> 2) * 64, wn = (wid & 3) * 64;
  const int ml = lane & 15, quad = lane >> 4;

  f32x4 acc[4][4] = {};

  const int ra = tid >> 2, ca0 = (tid & 3) * 2;
  int rag = m0 + ra; if (rag >= M) rag = M - 1;   // clamp: garbage rows never stored
  const float* aRow = A + (size_t)rag * 256;
  const int rw = tid >> 1, hw = tid & 1;
  const u16* wRow = Wb + (size_t)rw * 256;

  for (int k0 = 0; k0 < 256; k0 += 64){
    #pragma unroll
    for (int q = 0; q < 2; q++){
      int ch = ca0 + q;
      f32x4 v0 = __builtin_nontemporal_load((const f32x4*)(aRow + k0 + ch * 8));
      f32x4 v1 = __builtin_nontemporal_load((const f32x4*)(aRow + k0 + ch * 8 + 4));
      ushort4 h0 = make_ushort4(f2bf(v0[0]), f2bf(v0[1]), f2bf(v0[2]), f2bf(v0[3]));
      ushort4 h1 = make_ushort4(f2bf(v1[0]), f2bf(v1[1]), f2bf(v1[2]), f2bf(v1[3]));
      u16* p = As + ra * 64 + ((ch ^ (ra & 7)) * 8);
      *(ushort4*)p = h0;
      *(ushort4*)(p + 4) = h1;
    }
    #pragma unroll
    for (int q = 0; q < 4; q++){
      int ch = hw * 4 + q;
      uint4 wv = *(const uint4*)(wRow + k0 + ch * 8);
      *(uint4*)(Ws + rw * 64 + ((ch ^ (rw & 7)) * 8)) = wv;
    }
    __syncthreads();
    #pragma unroll
    for (int kk = 0; kk < 64; kk += 32){
      bf16x8 af[4], wf[4];
      const int cA = (kk >> 3) + quad;
      #pragma unroll
      for (int t = 0; t < 4; t++){
        int r = wm + t * 16 + ml;
        af[t] = *(const bf16x8*)(As + r * 64 + ((cA ^ (r & 7)) * 8));
      }
      #pragma unroll
      for (int t = 0; t < 4; t++){
        int n = wn + t * 16 + ml;
        wf[t] = *(const bf16x8*)(Ws + n * 64 + ((cA ^ (n & 7)) * 8));
      }
      #pragma unroll
      for (int i = 0; i < 4; i++)
        #pragma unroll
        for (int j = 0; j < 4; j++)
          acc[i][j] = __builtin_amdgcn_mfma_f32_16x16x32_bf16(af[i], wf[j], acc[i][j], 0, 0, 0);
    }
    __syncthreads();
  }
  const size_t qoff = (size_t)(wn >> 6) * NND * 64;
  #pragma unroll
  for (int i = 0; i < 4; i++){
    #pragma unroll
    for (int rr = 0; rr < 4; rr++){
      int row = m0 + wm + i * 16 + quad * 4 + rr;
      if (row < M){
        u16* crow = C + qoff + (size_t)row * 64;
        #pragma unroll
        for (int j = 0; j < 4; j++)
          __builtin_nontemporal_store(f2bf(acc[i][j][rr]), crow + j * 16 + ml);
      }
    }
  }
}

// ---------------- hist: per-(chunk, bin) edge counts. LDS histogram -- ZERO
// global atomics (round-6 lesson: per-edge global ret-atomics ~50us; round-7
// lesson: LDS **int** atomics cheap, LDS **float** atomicAdd = CAS disaster).
__global__ __launch_bounds__(256) void hist_k(const int* __restrict__ dst,
                                              int* __restrict__ mat){
  __shared__ int h[NBIN];
  int b = blockIdx.x, tid = threadIdx.x;
  for (int i = tid; i < NBIN; i += 256) h[i] = 0;
  __syncthreads();
  int base = b * CHK;
  #pragma unroll
  for (int j = 0; j < CHK / 256; j++){
    int e = base + j * 256 + tid;
    if (e < NE) atomicAdd(&h[dst[e] >> 6], 1);
  }
  __syncthreads();
  for (int i = tid; i < NBIN; i += 256) mat[i * NCH + b] = h[i];
}

// ---------------- scan over NM entries -> local offsets + block sums
__global__ __launch_bounds__(256) void scan1_k(const int* __restrict__ in,
                                               int* __restrict__ out,
                                               int* __restrict__ bsum){
  __shared__ int lds[256];
  int b = blockIdx.x, tid = threadIdx.x;
  int base = b * 1024 + tid * 4;
  int d[4]; int tsum = 0;
  #pragma unroll
  for (int j = 0; j < 4; j++){
    int v = (base + j < NM) ? in[base + j] : 0;
    d[j] = tsum; tsum += v;
  }
  lds[tid] = tsum; __syncthreads();
  for (int off = 1; off < 256; off <<= 1){
    int v = (tid >= off) ? lds[tid - off] : 0;
    __syncthreads();
    lds[tid] += v;
    __syncthreads();
  }
  int excl = lds[tid] - tsum;
  #pragma unroll
  for (int j = 0; j < 4; j++)
    if (base + j < NM) out[base + j] = excl + d[j];
  if (tid == 255) bsum[b] = lds[tid];
}

__global__ __launch_bounds__(256) void scan2_k(const int* __restrict__ bsum,
                                               int* __restrict__ bbase, int nb){
  __shared__ int l[256];
  int tid = threadIdx.x;
  int v = (tid < nb) ? bsum[tid] : 0;
  l[tid] = v; __syncthreads();
  for (int off = 1; off < 256; off <<= 1){
    int u = (tid >= off) ? l[tid - off] : 0;
    __syncthreads();
    l[tid] += u;
    __syncthreads();
  }
  bbase[tid] = l[tid] - v;
}

// ---------------- scatter into bin-contiguous ebuf via LDS int cursors
// entry = (dlow6 << 19) | (src16 << 3) | etype3
__global__ __launch_bounds__(256) void scat_k(const int* __restrict__ dst,
                                              const int* __restrict__ src,
                                              const int* __restrict__ ef,
                                              const int* __restrict__ mscan,
                                              const int* __restrict__ bbase,
                                              int* __restrict__ ebuf){
  __shared__ int cur[NBIN];
  int b = blockIdx.x, tid = threadIdx.x;
  for (int i = tid; i < NBIN; i += 256){
    int m = i * NCH + b;
    cur[i] = mscan[m] + bbase[m >> 10];
  }
  __syncthreads();
  int base = b * CHK;
  #pragma unroll
  for (int j = 0; j < CHK / 256; j++){
    int e = base + j * 256 + tid;
    if (e < NE){
      int d = dst[e];
      int r = atomicAdd(&cur[d >> 6], 1);   // LDS int ret-atomic: cheap
      ebuf[r] = ((d & 63) << 19) | (src[e] << 3) | ef[e];
    }
  }
}

// ---------------- sort: per-bin counting sort by dlow -> node-ordered csr +
// dense nodeoffs. Two passes over the bin's contiguous ebuf run (no staging
// cap); LDS int atomics only. Gives agg the per-node (s,e) runs round 4 used.
__global__ __launch_bounds__(256) void sort_k(const int* __restrict__ ebuf,
                                              const int* __restrict__ mscan,
                                              const int* __restrict__ bbase,
                                              int* __restrict__ csr,
                                              int* __restrict__ nodeoffs){
  __shared__ int h[64], hc[64];
  int b = blockIdx.x, tid = threadIdx.x;
  int m0 = b * NCH;
  int s = mscan[m0] + bbase[m0 >> 10];
  int e;
  if (b == NBIN - 1) e = NE;
  else { int m1 = (b + 1) * NCH; e = mscan[m1] + bbase[m1 >> 10]; }
  if (tid < 64) h[tid] = 0;
  __syncthreads();
  for (int i = s + tid; i < e; i += 256)
    atomicAdd(&h[(ebuf[i] >> 19) & 63], 1);
  __syncthreads();
  if (tid == 0){
    int acc = 0;
    for (int k = 0; k < 64; k++){ int t = h[k]; hc[k] = acc; acc += t; }
  }
  __syncthreads();
  if (tid < 64){
    int node = b * 64 + tid;
    if (node < NND) nodeoffs[node] = s + hc[tid];
  }
  if (b == NBIN - 1 && tid == 0) nodeoffs[NND] = NE;
  __syncthreads();
  for (int i = s + tid; i < e; i += 256){
    int p = ebuf[i];
    int r = atomicAdd(&hc[(p >> 19) & 63], 1);
    csr[s + r] = p;
  }
}

// ---------------- attn output: attn[e,h] = wl[type,h] * rdq[h>>1][dst][h&1]
__global__ __launch_bounds__(256) void attn_k(const int* __restrict__ dst,
                                              const int* __restrict__ ef,
                                              const float* __restrict__ rdq,
                                              const float* __restrict__ emb,
                                              float* __restrict__ attn){
  __shared__ float wl[40];
  int tid = threadIdx.x;
  if (tid < 40){
    int t = tid >> 3, h = tid & 7;
    float m = emb[h];
    for (int tt = 1; tt < NTY; ++tt) m = fmaxf(m, emb[tt * 8 + h]);
    wl[tid] = expf(emb[t * 8 + h] - m);
  }
  __syncthreads();
  int e = blockIdx.x * 256 + tid;
  if (e >= NE) return;
  int d = dst[e], t = ef[e];
  const float* wr = wl + t * 8;
  f32x4 o0, o1;
  #pragma unroll
  for (int q = 0; q < 4; q++){
    float2 rv = *(const float2*)(rdq + ((size_t)q * NND + d) * 2);
    float a = wr[2 * q] * rv.x, bb = wr[2 * q + 1] * rv.y;
    if (q < 2){ o0[2 * q] = a; o0[2 * q + 1] = bb; }
    else      { o1[2 * (q - 2)] = a; o1[2 * (q - 2) + 1] = bb; }
  }
  __builtin_nontemporal_store(o0, (f32x4*)(attn + (size_t)e * 8));
  __builtin_nontemporal_store(o1, (f32x4*)(attn + (size_t)e * 8 + 4));
}

// ---------------- aggregation: ROUND-4 VERIFIED BODY (49.2us). 8 lanes/node x
// 16B = one 128B line/edge (request floor); XCD-pinned pair-quarters; REGISTER
// accumulation (round-7 lesson: never LDS float atomics); nt-stores. (s,e)
// now from dense nodeoffs (2 scalar L2-hit loads, replaces cursor/deg4 int4s).
__device__ inline void acc8(uint4 v, float wt, f32x2* a){
  f32x2 w2; w2.x = wt; w2.y = wt;
  f32x2 t0; t0.x = __uint_as_float(v.x << 16); t0.y = __uint_as_float(v.x & 0xFFFF0000u);
  f32x2 t1; t1.x = __uint_as_float(v.y << 16); t1.y = __uint_as_float(v.y & 0xFFFF0000u);
  f32x2 t2; t2.x = __uint_as_float(v.z << 16); t2.y = __uint_as_float(v.z & 0xFFFF0000u);
  f32x2 t3; t3.x = __uint_as_float(v.w << 16); t3.y = __uint_as_float(v.w & 0xFFFF0000u);
  a[0] += w2 * t0; a[1] += w2 * t1; a[2] += w2 * t2; a[3] += w2 * t3;
}

#define NBLK ((NND + 31) / 32)            // 1563 node-blocks per quarter
#define NBH  ((NBLK + 1) / 2)             // 782 per (quarter, xcd-half)

__global__ __launch_bounds__(256) void agg_k(const u16* __restrict__ fsrc,
                                             const int* __restrict__ csr,
                                             const int* __restrict__ nodeoffs,
                                             const float* __restrict__ emb,
                                             float* __restrict__ rst,
                                             float* __restrict__ rdq){
  __shared__ float wl[40];
  int tid = threadIdx.x;
  if (tid < 40){
    int t = tid >> 3, h = tid & 7;
    float m = emb[h];
    for (int tt = 1; tt < NTY; ++tt) m = fmaxf(m, emb[tt * 8 + h]);
    wl[tid] = expf(emb[t * 8 + h] - m);
  }
  __syncthreads();
  const int c  = blockIdx.x & 7;        // XCD (HW round-robin)
  const int q  = c >> 1;                // pair-quarter pinned to XCD pair
  const int nb = (blockIdx.x >> 3) * 2 + (c & 1);
  int node = nb * 32 + (tid >> 3);
  if (node >= NND) return;
  const int sl = tid & 7;               // 8 lanes/node, 16B each = 128B line
  const int h  = 2 * q + (sl >> 2);     // head this lane accumulates
  const u16* qbase = fsrc + (size_t)q * (NND * 64) + sl * 8;
  int s = nodeoffs[node];
  int e = nodeoffs[node + 1];
  f32x2 a[4]; a[0] = 0.f; a[1] = 0.f; a[2] = 0.f; a[3] = 0.f;
  float ss = 0.f;
  int i = s;
  for (; i + 3 < e; i += 4){
    int p0 = csr[i], p1 = csr[i+1], p2 = csr[i+2], p3 = csr[i+3];
    uint4 v0g = *(const uint4*)(qbase + ((size_t)((p0 >> 3) & 0xFFFF) << 6));
    uint4 v1g = *(const uint4*)(qbase + ((size_t)((p1 >> 3) & 0xFFFF) << 6));
    uint4 v2g = *(const uint4*)(qbase + ((size_t)((p2 >> 3) & 0xFFFF) << 6));
    uint4 v3g = *(const uint4*)(qbase + ((size_t)((p3 >> 3) & 0xFFFF) << 6));
    float w0 = wl[(p0 & 7) * 8 + h];
    float w1 = wl[(p1 & 7) * 8 + h];
    float w2 = wl[(p2 & 7) * 8 + h];
    float w3 = wl[(p3 & 7) * 8 + h];
    acc8(v0g, w0, a); acc8(v1g, w1, a); acc8(v2g, w2, a); acc8(v3g, w3, a);
    ss += (w0 + w1) + (w2 + w3);
  }
  for (; i < e; i++){
    int p0 = csr[i];
    uint4 v0g = *(const uint4*)(qbase + ((size_t)((p0 >> 3) & 0xFFFF) << 6));
    float w0 = wl[(p0 & 7) * 8 + h];
    acc8(v0g, w0, a);
    ss += w0;
  }
  float inv = 1.0f / (ss + 1e-12f);
  f32x4 o0, o1;
  o0[0] = a[0].x*inv; o0[1] = a[0].y*inv; o0[2] = a[1].x*inv; o0[3] = a[1].y*inv;
  o1[0] = a[2].x*inv; o1[1] = a[2].y*inv; o1[2] = a[3].x*inv; o1[3] = a[3].y*inv;
  float* orow = rst + (size_t)node * 256 + q * 64 + sl * 8;
  __builtin_nontemporal_store(o0, (f32x4*)orow);
  __builtin_nontemporal_store(o1, (f32x4*)(orow + 4));
  if ((sl & 3) == 0)
    __builtin_nontemporal_store(inv, rdq + ((size_t)q * NND + node) * 2 + (sl >> 2));
}

extern "C" void kernel_launch(void* const* d_in, const int* in_sizes, int n_in,
                              void* d_out, int out_size, void* d_ws, size_t ws_size,
                              hipStream_t stream) {
  const float* feat = (const float*)d_in[0];
  const float* fcw  = (const float*)d_in[1];
  const float* emb  = (const float*)d_in[2];
  const int*   ef   = (const int*)d_in[3];
  const int*   src  = (const int*)d_in[4];
  const int*   dst  = (const int*)d_in[5];

  float* rst  = (float*)d_out;                         // [50000, 8, 32]
  float* attn = (float*)d_out + (size_t)NND * NH * ND; // [800000, 8]

  char* ws = (char*)d_ws;
  size_t o = 0;
  u16* fsrc    = (u16*)(ws + o);   o += (size_t)NND * 256 * 2;   // 25.6 MB (pair-quarter-major)
  int* ebuf    = (int*)(ws + o);   o += (size_t)NE * 4;          // 3.2 MB (bin-contiguous)
  int* csr     = (int*)(ws + o);   o += (size_t)NE * 4;          // 3.2 MB (node-sorted)
  int* mat     = (int*)(ws + o);   o += (size_t)NM * 4 + 512;    // 613 KB
  int* mscan   = (int*)(ws + o);   o += (size_t)NM * 4 + 512;    // 613 KB
  float* rdq   = (float*)(ws + o); o += (size_t)NND * NH * 4;    // 1.6 MB [4][NND][2]
  int* nodeoffs= (int*)(ws + o);   o += (size_t)(NND + 1) * 4 + 252; // 200 KB
  u16* wb      = (u16*)(ws + o);   o += (size_t)256 * 256 * 2;   // 128 KB
  int* bsum    = (int*)(ws + o);   o += 1024;                    // 256 ints
  int* bbase   = (int*)(ws + o);   o += 1024;                    // 256 ints

  wcvt_k<<<64, 256, 0, stream>>>(fcw, wb);
  gemm_k<<<391, 512, 0, stream>>>(feat, wb, fsrc, NND);
  hist_k<<<NCH, 256, 0, stream>>>(dst, mat);
  scan1_k<<<(NM + 1023) / 1024, 256, 0, stream>>>(mat, mscan, bsum);
  scan2_k<<<1, 256, 0, stream>>>(bsum, bbase, (NM + 1023) / 1024);
  scat_k<<<NCH, 256, 0, stream>>>(dst, src, ef, mscan, bbase, ebuf);
  sort_k<<<NBIN, 256, 0, stream>>>(ebuf, mscan, bbase, csr, nodeoffs);
  agg_k<<<8 * NBH, 256, 0, stream>>>(fsrc, csr, nodeoffs, emb, rst, rdq);
  attn_k<<<(NE + 255) / 256, 256, 0, stream>>>(dst, ef, rdq, emb, attn);
}